// Round 1
// baseline (187.686 us; speedup 1.0000x reference)
//
#include <hip/hip_runtime.h>

// GaussianKernelRegression == flash attention:
//   logits s[n,m] = (q_n . t_m - 0.5*|t_m|^2) / std_n^2   (q_sq term drops in softmax)
//   out = softmax_m(s) @ source_db
// fp16x2 split GEMM (qh*th + qh*tl) for QK^T precision; fp16 PV. All MFMA 32x32x16_f16.
// t_sq folded into GEMM as extra k element (k=256: q_ext=1, t_ext=-0.5*t_sq), K padded to 272.
// Grid: 32 q-blocks x 8 M-chunks (bid&7=chunk -> chunk<->XCD affinity for L2 reuse).
// Block: 512 thr = 8 waves = 4 q-groups(32 rows) x {QK m-sub | PV d-half}.
// Swapped QK (mfma(T,Q^T)): D col=lane&31=q -> lane-local softmax stats.
// Per-chunk partials (O,m,l) in ws, combined by final kernel.

#define N_Q 4096
#define M_DB 16384
#define D_K 256
#define KP 272
#define NCH 17          // k-chunks of 16
#define BQ 128
#define BM 64
#define NCHUNK 8
#define MC (M_DB / NCHUNK)
#define NTILE (MC / BM)
#define LOG2E 1.44269504088896f

typedef _Float16 f16x8 __attribute__((ext_vector_type(8)));
typedef _Float16 f16x2 __attribute__((ext_vector_type(2)));
typedef float f32x16 __attribute__((ext_vector_type(16)));
typedef unsigned short u16;

// ---------- precompute: qh (fp16, k-padded, +1.0 at k=256) ----------
__global__ void k_prep_q(const float* __restrict__ q, u16* __restrict__ qh) {
  int n = blockIdx.x;
  int t = threadIdx.x;
  if (t < KP / 2) {
    int k0 = 2 * t;
    float v0 = (k0 < D_K) ? q[(size_t)n * D_K + k0] : (k0 == D_K ? 1.0f : 0.0f);
    float v1 = (k0 + 1 < D_K) ? q[(size_t)n * D_K + k0 + 1] : (k0 + 1 == D_K ? 1.0f : 0.0f);
    f16x2 p; p[0] = (_Float16)v0; p[1] = (_Float16)v1;
    *(f16x2*)(qh + (size_t)n * KP + k0) = p;
  }
}

// ---------- precompute: th/tl (fp16 hi/lo of t_ext, row-swizzled for k<256) ----------
__global__ void k_prep_t(const float* __restrict__ tdb, u16* __restrict__ th, u16* __restrict__ tl) {
  int m = blockIdx.x;
  int t = threadIdx.x; // 256
  float x = tdb[(size_t)m * D_K + t];
  float v = x * x;
#pragma unroll
  for (int off = 32; off >= 1; off >>= 1) v += __shfl_xor(v, off);
  __shared__ float red[4];
  int wid = t >> 6, lane = t & 63;
  if (lane == 0) red[wid] = v;
  __syncthreads();
  float tsq = red[0] + red[1] + red[2] + red[3];
  if (t < KP / 2) {
    int k0 = 2 * t;
    int sw = (m & 7) << 3;
    float v0 = (k0 < D_K) ? tdb[(size_t)m * D_K + k0] : (k0 == D_K ? -0.5f * tsq : 0.0f);
    float v1 = (k0 + 1 < D_K) ? tdb[(size_t)m * D_K + k0 + 1] : (k0 + 1 == D_K ? -0.5f * tsq : 0.0f);
    _Float16 h0 = (_Float16)v0, h1 = (_Float16)v1;
    f16x2 ph; ph[0] = h0; ph[1] = h1;
    f16x2 pl2; pl2[0] = (_Float16)(v0 - (float)h0); pl2[1] = (_Float16)(v1 - (float)h1);
    int ks = (k0 < D_K) ? (k0 ^ sw) : k0;  // swizzle only the 256-elem main region
    *(f16x2*)(th + (size_t)m * KP + ks) = ph;
    *(f16x2*)(tl + (size_t)m * KP + ks) = pl2;
  }
}

// ---------- precompute: vt[d][m] fp16, transposed + swizzled per 64-m window ----------
__global__ void k_prep_v(const float* __restrict__ src, u16* __restrict__ vt) {
  __shared__ float tile[64][65];
  int mb = blockIdx.x * 64, db = blockIdx.y * 64;
  int t = threadIdx.x; // 256
#pragma unroll
  for (int j = 0; j < 16; j++) {
    int idx = t + 256 * j;
    int ml = idx >> 6, dl = idx & 63;
    tile[ml][dl] = src[(size_t)(mb + ml) * D_K + db + dl];
  }
  __syncthreads();
#pragma unroll
  for (int i = 0; i < 8; i++) {
    int dl = (t >> 5) + 8 * i;
    int d = db + dl;
    int m0 = 2 * (t & 31);
    f16x2 p; p[0] = (_Float16)tile[m0][dl]; p[1] = (_Float16)tile[m0 + 1][dl];
    int ms = m0 ^ ((d & 7) << 3);
    *(f16x2*)(vt + (size_t)d * M_DB + mb + ms) = p;
  }
}

// ---------- main flash kernel ----------
__launch_bounds__(512, 2)
__global__ void k_main(const u16* __restrict__ qh, const u16* __restrict__ th,
                       const u16* __restrict__ tl, const u16* __restrict__ vt,
                       const float* __restrict__ stdv,
                       float* __restrict__ pO, float* __restrict__ pm, float* __restrict__ pl)
{
  __shared__ __align__(16) u16 lth[BM * KP];
  __shared__ __align__(16) u16 ltl[BM * KP];
  __shared__ __align__(16) u16 lvt[D_K * BM];
  __shared__ __align__(16) u16 lP[4 * 32 * BM];
  __shared__ float s_pmax[4][2][32];
  __shared__ float s_lsum[4][2][32];
  __shared__ float s_c[4][32];

  int bid = blockIdx.x;
  int chunk = bid & 7;
  int qblk = bid >> 3;
  int q0 = qblk * BQ;
  int tid = threadIdx.x;
  int lane = tid & 63, wid = tid >> 6;
  int g = wid >> 1, p = wid & 1;
  int lq = lane & 31, hi = lane >> 5;

  int qrow = q0 + 32 * g + lq;
  float sd = stdv[qrow];
  float is2l = LOG2E / (sd * sd);

  f16x8 qf[NCH];
#pragma unroll
  for (int c = 0; c < NCH; c++)
    qf[c] = *(const f16x8*)(qh + (size_t)qrow * KP + c * 16 + hi * 8);

  f32x16 accO[4];
#pragma unroll
  for (int dc = 0; dc < 4; dc++)
#pragma unroll
    for (int r = 0; r < 16; r++) accO[dc][r] = 0.f;

  float mrun = -3.0e38f, lrun = 0.f;

  int rowA = 32 * p + lq;
  int swA = (rowA & 7) << 4;
  int swP = (lq & 7) << 4;

  for (int tI = 0; tI < NTILE; tI++) {
    int mt = chunk * MC + tI * BM;
    // stage tiles (ws rows are pre-swizzled -> linear copy)
    {
      const uint4* s1 = (const uint4*)(th + (size_t)mt * KP);
      const uint4* s2 = (const uint4*)(tl + (size_t)mt * KP);
      uint4* d1 = (uint4*)lth;
      uint4* d2 = (uint4*)ltl;
      for (int i = tid; i < BM * KP / 8; i += 512) { d1[i] = s1[i]; d2[i] = s2[i]; }
#pragma unroll
      for (int j = 0; j < 4; j++) {
        int idx = tid + 512 * j;          // 2048 x 16B
        int dr = idx >> 3, sub = idx & 7;
        ((uint4*)lvt)[idx] = *(const uint4*)(vt + (size_t)dr * M_DB + mt + sub * 8);
      }
    }
    __syncthreads();

    // QK^T swapped: D[m_local][q], A=T rows (this wave's m-sub), B=Q (regs)
    f32x16 s;
#pragma unroll
    for (int r = 0; r < 16; r++) s[r] = 0.f;
#pragma unroll
    for (int c = 0; c < NCH; c++) {
      int ko = c * 32 + hi * 16;
      int kos = (c < 16) ? (ko ^ swA) : ko;
      f16x8 aH = *(const f16x8*)((const char*)lth + rowA * (KP * 2) + kos);
      f16x8 aL = *(const f16x8*)((const char*)ltl + rowA * (KP * 2) + kos);
      s = __builtin_amdgcn_mfma_f32_32x32x16_f16(aH, qf[c], s, 0, 0, 0);
      s = __builtin_amdgcn_mfma_f32_32x32x16_f16(aL, qf[c], s, 0, 0, 0);
    }
#pragma unroll
    for (int r = 0; r < 16; r++) s[r] *= is2l;   // base-2 logits

    float pmax = s[0];
#pragma unroll
    for (int r = 1; r < 16; r++) pmax = fmaxf(pmax, s[r]);
    pmax = fmaxf(pmax, __shfl_xor(pmax, 32));
    if (hi == 0) s_pmax[g][p][lq] = pmax;
    __syncthreads();

    float mnew = fmaxf(mrun, fmaxf(s_pmax[g][0][lq], s_pmax[g][1][lq]));
    float cl = exp2f(mrun - mnew);
    mrun = mnew;
    float ls = 0.f;
#pragma unroll
    for (int r = 0; r < 16; r++) { s[r] = exp2f(s[r] - mnew); ls += s[r]; }
    ls += __shfl_xor(ls, 32);
    if (hi == 0) {
      s_lsum[g][p][lq] = ls;
      if (p == 0) s_c[g][lq] = cl;
    }
    // P (fp16) -> LDS [g][q 32][m 64], swizzled rows
#pragma unroll
    for (int r = 0; r < 16; r += 2) {
      int m = 32 * p + (r & 3) + 8 * (r >> 2) + 4 * hi;
      f16x2 pk; pk[0] = (_Float16)s[r]; pk[1] = (_Float16)s[r + 1];
      *(f16x2*)((char*)lP + g * 4096 + lq * 128 + ((m * 2) ^ swP)) = pk;
    }
    __syncthreads();

    lrun = lrun * cl + s_lsum[g][0][lq] + s_lsum[g][1][lq];
#pragma unroll
    for (int r = 0; r < 16; r++) {
      float cr = s_c[g][(r & 3) + 8 * (r >> 2) + 4 * hi];
#pragma unroll
      for (int dc = 0; dc < 4; dc++) accO[dc][r] *= cr;
    }
    // PV: A=P[q][m] (LDS), B=vt[d][m] (LDS), O[q][d] d-half = p
#pragma unroll
    for (int kc = 0; kc < 4; kc++) {
      f16x8 pa = *(const f16x8*)((const char*)lP + g * 4096 + lq * 128 + ((kc * 32 + hi * 16) ^ swP));
#pragma unroll
      for (int dc = 0; dc < 4; dc++) {
        int d = p * 128 + dc * 32 + lq;
        f16x8 vb = *(const f16x8*)((const char*)lvt + d * 128 + ((kc * 32 + hi * 16) ^ ((d & 7) << 4)));
        accO[dc] = __builtin_amdgcn_mfma_f32_32x32x16_f16(pa, vb, accO[dc], 0, 0, 0);
      }
    }
    __syncthreads();
  }

  // partials
#pragma unroll
  for (int r = 0; r < 16; r++) {
    int row = q0 + 32 * g + (r & 3) + 8 * (r >> 2) + 4 * hi;
#pragma unroll
    for (int dc = 0; dc < 4; dc++) {
      int col = p * 128 + dc * 32 + lq;
      pO[((size_t)chunk * N_Q + row) * D_K + col] = accO[dc][r];
    }
  }
  if (p == 0 && hi == 0) {
    pm[(size_t)chunk * N_Q + qrow] = mrun;
    pl[(size_t)chunk * N_Q + qrow] = lrun;
  }
}

// ---------- combine chunk partials ----------
__global__ void k_combine(const float* __restrict__ pO, const float* __restrict__ pm,
                          const float* __restrict__ pl, float* __restrict__ out)
{
  int n = blockIdx.x, d = threadIdx.x;
  float M = -3.0e38f;
#pragma unroll
  for (int c = 0; c < NCHUNK; c++) M = fmaxf(M, pm[(size_t)c * N_Q + n]);
  float den = 0.f, num = 0.f;
#pragma unroll
  for (int c = 0; c < NCHUNK; c++) {
    float w = exp2f(pm[(size_t)c * N_Q + n] - M);
    den += w * pl[(size_t)c * N_Q + n];
    num += w * pO[((size_t)c * N_Q + n) * D_K + d];
  }
  out[(size_t)n * D_K + d] = num / den;
}

extern "C" void kernel_launch(void* const* d_in, const int* in_sizes, int n_in,
                              void* d_out, int out_size, void* d_ws, size_t ws_size,
                              hipStream_t stream)
{
  const float* q    = (const float*)d_in[0];
  const float* stdv = (const float*)d_in[1];
  const float* src  = (const float*)d_in[2];   // source_db (V)
  const float* tdb  = (const float*)d_in[3];   // target_db (T)
  float* out = (float*)d_out;

  char* w = (char*)d_ws;
  u16* qh = (u16*)w;      w += (size_t)N_Q * KP * 2;
  u16* th = (u16*)w;      w += (size_t)M_DB * KP * 2;
  u16* tl = (u16*)w;      w += (size_t)M_DB * KP * 2;
  u16* vt = (u16*)w;      w += (size_t)D_K * M_DB * 2;
  float* pO = (float*)w;  w += (size_t)NCHUNK * N_Q * D_K * 4;
  float* pm = (float*)w;  w += (size_t)NCHUNK * N_Q * 4;
  float* pl = (float*)w;  w += (size_t)NCHUNK * N_Q * 4;

  hipLaunchKernelGGL(k_prep_q, dim3(N_Q), dim3(256), 0, stream, q, qh);
  hipLaunchKernelGGL(k_prep_t, dim3(M_DB), dim3(256), 0, stream, tdb, th, tl);
  hipLaunchKernelGGL(k_prep_v, dim3(M_DB / 64, 4), dim3(256), 0, stream, src, vt);
  hipLaunchKernelGGL(k_main, dim3(32 * NCHUNK), dim3(512), 0, stream,
                     qh, th, tl, vt, stdv, pO, pm, pl);
  hipLaunchKernelGGL(k_combine, dim3(N_Q), dim3(256), 0, stream, pO, pm, pl, out);
}

// Round 2
// 185.334 us; speedup vs baseline: 1.0127x; 1.0127x over previous
//
#include <hip/hip_runtime.h>

// GaussianKernelRegression == flash attention:
//   s[n,m] = (q_n . t_m - 0.5*|t_m|^2) / std_n^2  (q^2 drops in softmax)
//   out = softmax_m(s) @ source_db
// V3: 1024-thr blocks = 16 waves = 8 q-groups(16q) x 2 p(m-half for QK, d-half for PV).
// BQ=128, BM=32, KP=256 (t_sq applied as exact f32 bias, not folded into GEMM).
// fp16 hi/lo split T (2 MFMA per k-chunk) for precision; MFMA 16x16x32_f16.
// All operands pre-packed into MFMA fragment "blobs" (1KB = 64 lanes x 16B) so
// every LDS read is base+lane*16 (conflict-free) and staging is global_load_lds.
// Double-buffered staging: issue for t+1 at start of t; mid-tile barriers are raw
// s_barrier+lgkmcnt(0) (no vmcnt drain) so staged loads fly across them; the
// end-of-tile __syncthreads drains vmcnt. Per-chunk partials (flash-decoding)
// combined by k_combine.

#define N_Q 4096
#define M_DB 16384
#define D_K 256
#define BQ 128
#define BM 32
#define NCHUNK 8
#define MC (M_DB / NCHUNK)   // 2048
#define NTILE (MC / BM)      // 64
#define NCH 8                // k-chunks of 32
#define LOG2E 1.44269504088896f

typedef _Float16 f16;
typedef _Float16 f16x4v __attribute__((ext_vector_type(4)));
typedef _Float16 f16x8 __attribute__((ext_vector_type(8)));
typedef float f32x4 __attribute__((ext_vector_type(4)));
typedef unsigned short u16;

typedef const __attribute__((address_space(1))) void cg_void;
typedef __attribute__((address_space(3))) void lds_void;

__device__ __forceinline__ void gload16(const void* g, void* s) {
  __builtin_amdgcn_global_load_lds((cg_void*)g, (lds_void*)s, 16, 0, 0);
}

// ---------- prep: Q fragment blobs. qpk[qt][c] blob: lane l byte e2 -> Q[qt*16+(l&15)][c*32+(l>>4)*8+e]
__global__ void k_prep_q(const float* __restrict__ q, u16* __restrict__ qpk) {
  int qt = blockIdx.x;
  int t = threadIdx.x;
#pragma unroll
  for (int i = 0; i < 2; i++) {
    int slot = t + 256 * i;            // c*64 + l
    int c = slot >> 6, l = slot & 63;
    int row = qt * 16 + (l & 15);
    int k0 = c * 32 + ((l >> 4) & 3) * 8;
    const float* src = q + (size_t)row * D_K + k0;
    f16x8 o;
#pragma unroll
    for (int e = 0; e < 8; e++) o[e] = (f16)src[e];
    *(f16x8*)(qpk + (size_t)qt * 4096 + slot * 8) = o;
  }
}

// ---------- prep: 0.5 * row-sum-sq of target_db
__global__ void k_prep_tq(const float* __restrict__ tdb, float* __restrict__ tq) {
  int t = threadIdx.x;
  int row = blockIdx.x * 8 + (t >> 5);
  int ln = t & 31;
  float s = 0.f;
#pragma unroll
  for (int i = 0; i < 8; i++) { float x = tdb[(size_t)row * D_K + ln + 32 * i]; s += x * x; }
#pragma unroll
  for (int off = 16; off >= 1; off >>= 1) s += __shfl_xor(s, off);
  if (ln == 0) tq[row] = 0.5f * s;
}

// ---------- prep: T fragment blobs (hi/lo fp16 split). chunk = p*1024 + c*128 + hl*64 + l
__global__ void k_prep_t(const float* __restrict__ tdb, u16* __restrict__ pkT) {
  int ti = blockIdx.x;
  int t = threadIdx.x;
#pragma unroll
  for (int i = 0; i < 8; i++) {
    int ck = t + 256 * i;
    int l = ck & 63, hl = (ck >> 6) & 1, c = (ck >> 7) & 7, p = (ck >> 10) & 1;
    int row = ti * 32 + p * 16 + (l & 15);
    int k0 = c * 32 + ((l >> 4) & 3) * 8;
    const float* src = tdb + (size_t)row * D_K + k0;
    f16x8 o;
#pragma unroll
    for (int e = 0; e < 8; e++) {
      float v = src[e];
      f16 h = (f16)v;
      o[e] = hl ? (f16)(v - (float)h) : h;
    }
    *(f16x8*)(pkT + (size_t)ti * 16384 + ck * 8) = o;   // 32KB per tile
  }
}

// ---------- prep: V fragment blobs. chunk = dc*64 + l: lane l byte e2 -> V[ti*32+(l>>4)*8+e][dc*16+(l&15)]
__global__ void k_prep_v(const float* __restrict__ src, u16* __restrict__ pkV) {
  int ti = blockIdx.x;
  int t = threadIdx.x;
#pragma unroll
  for (int i = 0; i < 4; i++) {
    int ck = t + 256 * i;
    int l = ck & 63, dc = ck >> 6;
    int colg = dc * 16 + (l & 15);
    int rb = ti * 32 + ((l >> 4) & 3) * 8;
    f16x8 o;
#pragma unroll
    for (int e = 0; e < 8; e++) o[e] = (f16)src[(size_t)(rb + e) * D_K + colg];
    *(f16x8*)(pkV + (size_t)ti * 8192 + ck * 8) = o;    // 16KB per tile
  }
}

// ---------- main flash kernel ----------
__launch_bounds__(1024, 4)
__global__ void k_main(const u16* __restrict__ qpk, const u16* __restrict__ pkT,
                       const u16* __restrict__ pkV, const float* __restrict__ tq,
                       const float* __restrict__ stdv,
                       float* __restrict__ pO, float* __restrict__ pm, float* __restrict__ pl)
{
  __shared__ __align__(16) char su[2][49152];   // [T 32KB | V 16KB] double-buffered
  __shared__ __align__(16) char lP[8192];       // 8 qg x 1KB P fragment blobs
  __shared__ float s_pmax[8][2][16];
  __shared__ float s_lsum[8][2][16];
  __shared__ __align__(16) float s_cf[8][16];
  __shared__ __align__(16) float s_tq[2][32];

  const int bid = blockIdx.x, chunk = bid & 7, qblk = bid >> 3;
  const int tid = threadIdx.x;
  const int w = tid >> 6, l = tid & 63;
  const int qg = w >> 1, p = w & 1;
  const int lq = l & 15, mg = (l >> 4) & 3;

  const int qrow = qblk * BQ + qg * 16 + lq;
  const float sd = stdv[qrow];
  const float is2l = LOG2E / (sd * sd);

  // Q fragments in registers (32 VGPRs)
  f16x8 qf[NCH];
  {
    const u16* qb = qpk + (size_t)(qblk * 8 + qg) * 4096 + l * 8;
#pragma unroll
    for (int c = 0; c < NCH; c++) qf[c] = *(const f16x8*)(qb + c * 512);
  }

  f32x4 acc[8];
#pragma unroll
  for (int j = 0; j < 8; j++) acc[j] = (f32x4){0.f, 0.f, 0.f, 0.f};
  float mrun = -3.0e38f, lrun = 0.f;

  const size_t tbase = (size_t)chunk * NTILE;

  // prologue: stage tile 0 into buffer 0
  {
    const char* gT = (const char*)pkT + (tbase + 0) * 32768;
    const char* gV = (const char*)pkV + (tbase + 0) * 16384;
    char* sdst = &su[0][0] + w * 1024;   // wave-uniform LDS base, lane*16 implicit
    gload16(gT + tid * 16, sdst);
    gload16(gT + 16384 + tid * 16, sdst + 16384);
    gload16(gV + tid * 16, sdst + 32768);
    if (tid < 32) s_tq[0][tid] = tq[chunk * MC + tid];
  }
  __syncthreads();

  for (int t = 0; t < NTILE; ++t) {
    const int cur = t & 1, nxt = cur ^ 1;
    const bool hasNext = (t + 1 < NTILE);
    float tqv = 0.f;
    if (hasNext) {   // issue next-tile staging; drained only at end-of-tile syncthreads
      const char* gT = (const char*)pkT + (tbase + t + 1) * 32768;
      const char* gV = (const char*)pkV + (tbase + t + 1) * 16384;
      char* sdst = &su[nxt][0] + w * 1024;
      gload16(gT + tid * 16, sdst);
      gload16(gT + 16384 + tid * 16, sdst + 16384);
      gload16(gV + tid * 16, sdst + 32768);
      if (tid < 32) tqv = tq[chunk * MC + (t + 1) * BM + tid];  // carried in reg, LDS-stored late
    }

    // ---- QK^T (swapped: A=T m-rows, B=Q q-cols -> D[m][q], col=lane&15=q) ----
    f32x4 s = {0.f, 0.f, 0.f, 0.f};
    const char* tb = &su[cur][0] + p * 16384 + l * 16;
#pragma unroll
    for (int c = 0; c < NCH; c++) {
      f16x8 aH = *(const f16x8*)(tb + c * 2048);
      f16x8 aL = *(const f16x8*)(tb + c * 2048 + 1024);
      s = __builtin_amdgcn_mfma_f32_16x16x32_f16(aH, qf[c], s, 0, 0, 0);
      s = __builtin_amdgcn_mfma_f32_16x16x32_f16(aL, qf[c], s, 0, 0, 0);
    }
    const f32x4 t4 = *(const f32x4*)&s_tq[cur][p * 16 + mg * 4];
    float l2[4];
#pragma unroll
    for (int r = 0; r < 4; r++) l2[r] = (s[r] - t4[r]) * is2l;   // base-2 logits
    float px = fmaxf(fmaxf(l2[0], l2[1]), fmaxf(l2[2], l2[3]));
    px = fmaxf(px, __shfl_xor(px, 16));
    px = fmaxf(px, __shfl_xor(px, 32));
    if (l < 16) s_pmax[qg][p][l] = px;

    // B1: raw barrier (keeps staging in flight)
    asm volatile("s_waitcnt lgkmcnt(0)" ::: "memory");
    __builtin_amdgcn_s_barrier();
    asm volatile("" ::: "memory");

    const float mnew = fmaxf(mrun, fmaxf(s_pmax[qg][0][lq], s_pmax[qg][1][lq]));
    const float cl = exp2f(mrun - mnew);
    mrun = mnew;
    float pr[4]; float ls = 0.f;
#pragma unroll
    for (int r = 0; r < 4; r++) { pr[r] = exp2f(l2[r] - mnew); ls += pr[r]; }
    ls += __shfl_xor(ls, 16);
    ls += __shfl_xor(ls, 32);
    if (l < 16) { s_lsum[qg][p][l] = ls; if (p == 0) s_cf[qg][l] = cl; }
    {
      // P -> A-fragment blob: byte(q,m) = (m>>3)*256 + q*16 + (m&7)*2, m = p*16+mg*4+r
      f16x4v pk;
      pk[0] = (f16)pr[0]; pk[1] = (f16)pr[1]; pk[2] = (f16)pr[2]; pk[3] = (f16)pr[3];
      *(f16x4v*)(&lP[0] + qg * 1024 + lq * 16 + (p * 2 + (mg >> 1)) * 256 + (mg & 1) * 8) = pk;
    }

    // B2
    asm volatile("s_waitcnt lgkmcnt(0)" ::: "memory");
    __builtin_amdgcn_s_barrier();
    asm volatile("" ::: "memory");

    lrun = lrun * cl + s_lsum[qg][0][lq] + s_lsum[qg][1][lq];
    const f32x4 c4 = *(const f32x4*)&s_cf[qg][mg * 4];   // rescale factors in acc-geometry
#pragma unroll
    for (int j = 0; j < 8; j++) {
#pragma unroll
      for (int r = 0; r < 4; r++) acc[j][r] *= c4[r];
    }
    // ---- PV: A=P (one K=32 frag, reused for all dc), B=V blobs, d-half = p ----
    const f16x8 pa = *(const f16x8*)(&lP[0] + qg * 1024 + l * 16);
    const char* vb0 = &su[cur][0] + 32768 + p * 8192 + l * 16;
#pragma unroll
    for (int j = 0; j < 8; j++) {
      f16x8 vb = *(const f16x8*)(vb0 + j * 1024);
      acc[j] = __builtin_amdgcn_mfma_f32_16x16x32_f16(pa, vb, acc[j], 0, 0, 0);
    }
    if (hasNext && tid < 32) s_tq[nxt][tid] = tqv;
    __syncthreads();   // B3: drains vmcnt (staged tile ready) + syncs P/stat buffers
  }

  // ---- partials (flash-decoding combine across chunks) ----
#pragma unroll
  for (int j = 0; j < 8; j++) {
    const int d = p * 128 + j * 16 + lq;
#pragma unroll
    for (int r = 0; r < 4; r++) {
      const int row = qblk * BQ + qg * 16 + mg * 4 + r;
      pO[((size_t)chunk * N_Q + row) * D_K + d] = acc[j][r];
    }
  }
  if (p == 0 && l < 16) {
    pm[(size_t)chunk * N_Q + qrow] = mrun;
    pl[(size_t)chunk * N_Q + qrow] = lrun;
  }
}

// ---------- combine chunk partials ----------
__global__ void k_combine(const float* __restrict__ pO, const float* __restrict__ pm,
                          const float* __restrict__ pl, float* __restrict__ out)
{
  int n = blockIdx.x, d = threadIdx.x;
  float M = -3.0e38f;
#pragma unroll
  for (int c = 0; c < NCHUNK; c++) M = fmaxf(M, pm[(size_t)c * N_Q + n]);
  float den = 0.f, num = 0.f;
#pragma unroll
  for (int c = 0; c < NCHUNK; c++) {
    float w = exp2f(pm[(size_t)c * N_Q + n] - M);
    den += w * pl[(size_t)c * N_Q + n];
    num += w * pO[((size_t)c * N_Q + n) * D_K + d];
  }
  out[(size_t)n * D_K + d] = num / den;
}

extern "C" void kernel_launch(void* const* d_in, const int* in_sizes, int n_in,
                              void* d_out, int out_size, void* d_ws, size_t ws_size,
                              hipStream_t stream)
{
  const float* q    = (const float*)d_in[0];
  const float* stdv = (const float*)d_in[1];
  const float* src  = (const float*)d_in[2];   // source_db (V)
  const float* tdb  = (const float*)d_in[3];   // target_db (T)
  float* out = (float*)d_out;

  char* wsp = (char*)d_ws;
  u16* qpk = (u16*)wsp;   wsp += (size_t)N_Q * D_K * 2;            // 2 MB
  u16* pkT = (u16*)wsp;   wsp += (size_t)M_DB * D_K * 2 * 2;       // 16.8 MB (hi+lo)
  u16* pkV = (u16*)wsp;   wsp += (size_t)M_DB * D_K * 2;           // 8.4 MB
  float* tq = (float*)wsp; wsp += (size_t)M_DB * 4;                // 64 KB
  float* pO = (float*)wsp; wsp += (size_t)NCHUNK * N_Q * D_K * 4;  // 33.5 MB
  float* pm = (float*)wsp; wsp += (size_t)NCHUNK * N_Q * 4;
  float* pl = (float*)wsp; wsp += (size_t)NCHUNK * N_Q * 4;

  hipLaunchKernelGGL(k_prep_q,  dim3(N_Q / 16), dim3(256), 0, stream, q, qpk);
  hipLaunchKernelGGL(k_prep_tq, dim3(M_DB / 8), dim3(256), 0, stream, tdb, tq);
  hipLaunchKernelGGL(k_prep_t,  dim3(M_DB / 32), dim3(256), 0, stream, tdb, pkT);
  hipLaunchKernelGGL(k_prep_v,  dim3(M_DB / 32), dim3(256), 0, stream, src, pkV);
  hipLaunchKernelGGL(k_main,    dim3(32 * NCHUNK), dim3(1024), 0, stream,
                     qpk, pkT, pkV, tq, stdv, pO, pm, pl);
  hipLaunchKernelGGL(k_combine, dim3(N_Q), dim3(256), 0, stream, pO, pm, pl, out);
}